// Round 6
// baseline (366.025 us; speedup 1.0000x reference)
//
#include <hip/hip_runtime.h>
#include <hip/hip_bf16.h>
#include <math.h>

// Problem constants
#define NROWS 8192
#define DDAT  784
#define LDK_D 800            // padded K (multiple of 32)
#define DLAT  64
#define TILE  128            // output tile per block
#define NBT   64             // zz grid dim: 8192/128
#define NPARTS (NBT * NBT)   // 4096 zz partial slots
#define NBTC  128            // concat rows 16384 / 128
#define NTRI  (NBTC * (NBTC + 1) / 2)   // 8256 upper-triangle blocks

typedef __attribute__((ext_vector_type(8))) short bf16x8;
typedef __attribute__((ext_vector_type(4))) float f32x4;

__device__ __forceinline__ void gload_lds16(const void* g, void* l) {
    __builtin_amdgcn_global_load_lds(
        (const __attribute__((address_space(1))) unsigned int*)g,
        (__attribute__((address_space(3))) unsigned int*)l,
        16 /*bytes*/, 0, 0);
}

// ---------------------------------------------------------------------------
// fp32 -> bf16 (zero-padded to LDK) + exact fp32 row norms, fused.
// grid = (8192, 3), block = 256.
// ---------------------------------------------------------------------------
__global__ void convert_kernel(const float* __restrict__ dat,
                               const float* __restrict__ rec,
                               const float* __restrict__ z,
                               unsigned short* __restrict__ dat_bf,
                               unsigned short* __restrict__ rec_bf,
                               unsigned short* __restrict__ z_bf,
                               float* __restrict__ a2d,
                               float* __restrict__ a2r,
                               float* __restrict__ a2z)
{
    const float* X; unsigned short* O; float* N2; int D, LDK;
    if (blockIdx.y == 0)      { X = dat; O = dat_bf; N2 = a2d; D = DDAT; LDK = LDK_D; }
    else if (blockIdx.y == 1) { X = rec; O = rec_bf; N2 = a2r; D = DDAT; LDK = LDK_D; }
    else                      { X = z;   O = z_bf;   N2 = a2z; D = DLAT; LDK = DLAT; }

    const int row = blockIdx.x;
    float s = 0.f;
    for (int k = threadIdx.x; k < LDK; k += 256) {
        float v = (k < D) ? X[(size_t)row * D + k] : 0.f;
        __hip_bfloat16 h = __float2bfloat16(v);
        O[(size_t)row * LDK + k] = *reinterpret_cast<unsigned short*>(&h);
        s += v * v;
    }
    __shared__ float sm[256];
    sm[threadIdx.x] = s;
    __syncthreads();
    for (int off = 128; off > 0; off >>= 1) {
        if (threadIdx.x < off) sm[threadIdx.x] += sm[threadIdx.x + off];
        __syncthreads();
    }
    if (threadIdx.x == 0) N2[row] = sm[0];
}

// ---------------------------------------------------------------------------
// [fast path] Merged triangular MFMA pairwise-phi kernel over the
// concatenated [data; rec] bf16 matrix (16384 x LDK_D).
// 1D grid of NTRI=8256 upper-triangle 128x128 blocks (by <= bx).
// Regions: 0 = dd (bx<64), 1 = rr (by>=64), 2 = dr (mixed, covers C once).
// Symmetric regions: off-diagonal blocks weighted x2.
//
// Pipeline: 2-phase double-buffer — iter k stages buf[p^1] (tile k+1) BEFORE
// computing buf[p]; vmcnt(0)+barrier at iter end. Race-free by parity: the
// previous barrier proves all waves' reads of buf[p^1] completed.
//
// Bank-conflict fix (rule #21 both-sides): LDS stays linear (gload_lds
// requirement); the GLOBAL source k-chunk is permuted half ^= (row>>1)&3 and
// fragment reads apply the same involution slot = kg ^ ((lr>>1)&3), so
// 16-lane read groups cycle all 8 LDS 4-bank groups -> 2-way (free).
// ---------------------------------------------------------------------------
__global__ __launch_bounds__(256, 2)
void pair_mfma_tri(const unsigned short* __restrict__ cat,  // 16384 x LDK_D
                   const float* __restrict__ n2,            // 16384
                   float alpha, float beta,
                   double* __restrict__ part)               // 3 * NTRI
{
    const int bid = blockIdx.x;
    int by = 0, rem = bid;                 // triangular decode, by <= bx
    while (rem >= NBTC - by) { rem -= NBTC - by; ++by; }
    const int bx = by + rem;

    int region; float w;
    if (bx < NBTC / 2)       { region = 0; w = (bx == by) ? 1.f : 2.f; }
    else if (by >= NBTC / 2) { region = 1; w = (bx == by) ? 1.f : 2.f; }
    else                     { region = 2; w = 1.f; }

    const int t    = threadIdx.x;
    const int lane = t & 63;
    const int wave = t >> 6;
    const int wm = wave >> 1;    // wave row (0..1)
    const int wn = wave & 1;     // wave col (0..1)
    const size_t i0 = (size_t)by * TILE;
    const size_t j0 = (size_t)bx * TILE;

    __shared__ __align__(16) unsigned short As[2][TILE * 32];
    __shared__ __align__(16) unsigned short Bs[2][TILE * 32];

    f32x4 acc[4][4] = {};

    // Stage tile (K0) into buffer P. 512 x 16B chunks per matrix; chunk
    // g -> LDS slot (row=g>>2, half=g&3) at linear byte offset g*16;
    // global source chunk half-index swizzled: halfS = half ^ ((row>>1)&3).
    auto stage = [&](int P, int K0) {
#pragma unroll
        for (int s = 0; s < 2; ++s) {
            const int g     = s * 256 + t;
            const int row   = g >> 2;
            const int halfS = (g & 3) ^ ((row >> 1) & 3);
            const int ldsbase = (s * 256 + wave * 64) * 8;   // in shorts
            gload_lds16(&cat[(i0 + row) * LDK_D + K0 + halfS * 8], &As[P][ldsbase]);
            gload_lds16(&cat[(j0 + row) * LDK_D + K0 + halfS * 8], &Bs[P][ldsbase]);
        }
    };

    // Prologue: stage tile 0, drain, barrier.
    stage(0, 0);
    asm volatile("s_waitcnt vmcnt(0)" ::: "memory");
    __builtin_amdgcn_sched_barrier(0);
    __syncthreads();

    int p = 0;
    for (int k0 = 0; k0 < LDK_D; k0 += 32) {
        if (k0 + 32 < LDK_D) stage(p ^ 1, k0 + 32);   // prefetch next tile

        const int lr   = lane & 15;
        const int kg   = lane >> 4;
        const int slot = kg ^ ((lr >> 1) & 3);        // read-side swizzle
        bf16x8 af[4], bfr[4];
#pragma unroll
        for (int m = 0; m < 4; ++m)
            af[m] = *reinterpret_cast<const bf16x8*>(
                &As[p][(wm * 64 + m * 16 + lr) * 32 + slot * 8]);
#pragma unroll
        for (int n = 0; n < 4; ++n)
            bfr[n] = *reinterpret_cast<const bf16x8*>(
                &Bs[p][(wn * 64 + n * 16 + lr) * 32 + slot * 8]);
#pragma unroll
        for (int m = 0; m < 4; ++m)
#pragma unroll
            for (int n = 0; n < 4; ++n)
                acc[m][n] = __builtin_amdgcn_mfma_f32_16x16x32_bf16(
                    af[m], bfr[n], acc[m][n], 0, 0, 0);

        // Drain prefetch (had the MFMA phase to land), then barrier.
        asm volatile("s_waitcnt vmcnt(0)" ::: "memory");
        __builtin_amdgcn_sched_barrier(0);
        __syncthreads();
        p ^= 1;
    }

    // Epilogue: C/D layout col = lane&15, row = (lane>>4)*4 + q  [m89/m91]
    float lsum = 0.f;
    const int cr = lane >> 4;
    const int cc = lane & 15;
#pragma unroll
    for (int m = 0; m < 4; ++m) {
#pragma unroll
        for (int n = 0; n < 4; ++n) {
#pragma unroll
            for (int q = 0; q < 4; ++q) {
                const int gi = (int)i0 + wm * 64 + m * 16 + cr * 4 + q;
                const int gj = (int)j0 + wn * 64 + n * 16 + cc;
                float d = n2[gi] + n2[gj] - 2.f * acc[m][n][q];
                d = fmaxf(d, 0.f);
                float x = alpha + beta * d;
                float r = __frsqrt_rn(x);
                r = r * (1.5f - 0.5f * x * r * r);   // one Newton step
                lsum += r;
            }
        }
    }
    lsum *= w;

    __shared__ float red[256];
    red[t] = lsum;
    __syncthreads();
    for (int off = 128; off > 0; off >>= 1) {
        if (t < off) red[t] += red[t + off];
        __syncthreads();
    }
    if (t == 0) part[(size_t)region * NTRI + bid] = (double)red[0];
}

// ---------------------------------------------------------------------------
// [fast path, zz] round-5 verified kernel, verbatim (small: K=64).
// ---------------------------------------------------------------------------
__global__ __launch_bounds__(256, 2)
void pair_mfma_fast(const unsigned short* __restrict__ A,
                    const unsigned short* __restrict__ B,
                    const float* __restrict__ a2,
                    const float* __restrict__ b2,
                    int LDK, float alpha, float beta, int sym,
                    double* __restrict__ part)
{
    const int bx = blockIdx.x;
    const int by = blockIdx.y;
    const int t  = threadIdx.x;
    if (sym && bx < by) {
        if (t == 0) part[(size_t)by * NBT + bx] = 0.0;
        return;
    }
    const int lane = t & 63;
    const int wave = t >> 6;
    const int wm = wave >> 1;
    const int wn = wave & 1;
    const int i0 = by * TILE;
    const int j0 = bx * TILE;

    __shared__ __align__(16) unsigned short As[2][TILE * 32];
    __shared__ __align__(16) unsigned short Bs[2][TILE * 32];

    f32x4 acc[4][4] = {};

    int p = 0;
    for (int k0 = 0; k0 < LDK; k0 += 32, p ^= 1) {
#pragma unroll
        for (int s = 0; s < 2; ++s) {
            const int g    = s * 256 + t;
            const int row  = g >> 2;
            const int half = g & 3;
            const int ldsbase = (s * 256 + wave * 64) * 8;
            gload_lds16(&A[(size_t)(i0 + row) * LDK + k0 + half * 8], &As[p][ldsbase]);
            gload_lds16(&B[(size_t)(j0 + row) * LDK + k0 + half * 8], &Bs[p][ldsbase]);
        }
        asm volatile("s_waitcnt vmcnt(0)" ::: "memory");
        __builtin_amdgcn_sched_barrier(0);
        __syncthreads();

        const int lr = lane & 15;
        const int kg = lane >> 4;
        bf16x8 af[4], bfr[4];
#pragma unroll
        for (int m = 0; m < 4; ++m)
            af[m] = *reinterpret_cast<const bf16x8*>(
                &As[p][(wm * 64 + m * 16 + lr) * 32 + kg * 8]);
#pragma unroll
        for (int n = 0; n < 4; ++n)
            bfr[n] = *reinterpret_cast<const bf16x8*>(
                &Bs[p][(wn * 64 + n * 16 + lr) * 32 + kg * 8]);
#pragma unroll
        for (int m = 0; m < 4; ++m)
#pragma unroll
            for (int n = 0; n < 4; ++n)
                acc[m][n] = __builtin_amdgcn_mfma_f32_16x16x32_bf16(
                    af[m], bfr[n], acc[m][n], 0, 0, 0);
    }

    float lsum = 0.f;
    const int cr = lane >> 4;
    const int cc = lane & 15;
#pragma unroll
    for (int m = 0; m < 4; ++m) {
#pragma unroll
        for (int n = 0; n < 4; ++n) {
#pragma unroll
            for (int q = 0; q < 4; ++q) {
                const int gi = i0 + wm * 64 + m * 16 + cr * 4 + q;
                const int gj = j0 + wn * 64 + n * 16 + cc;
                float d = a2[gi] + b2[gj] - 2.f * acc[m][n][q];
                d = fmaxf(d, 0.f);
                float x = alpha + beta * d;
                float r = __frsqrt_rn(x);
                r = r * (1.5f - 0.5f * x * r * r);
                lsum += r;
            }
        }
    }
    if (sym && bx > by) lsum *= 2.f;

    __shared__ float red[256];
    red[t] = lsum;
    __syncthreads();
    for (int off = 128; off > 0; off >>= 1) {
        if (t < off) red[t] += red[t + off];
        __syncthreads();
    }
    if (t == 0) part[(size_t)by * NBT + bx] = (double)red[0];
}

// ---------------------------------------------------------------------------
// [slow path fallback] round-3 verified reg-staged kernel, verbatim.
// ---------------------------------------------------------------------------
__global__ void rownorm_kernel(const float* __restrict__ dat,
                               const float* __restrict__ rec,
                               const float* __restrict__ z,
                               float* __restrict__ o_dat,
                               float* __restrict__ o_rec,
                               float* __restrict__ o_z)
{
    const float* X; float* O; int D;
    if (blockIdx.y == 0)      { X = dat; O = o_dat; D = DDAT; }
    else if (blockIdx.y == 1) { X = rec; O = o_rec; D = DDAT; }
    else                      { X = z;   O = o_z;   D = DLAT; }

    int row = blockIdx.x;
    float s = 0.f;
    for (int k = threadIdx.x; k < D; k += 256) {
        float v = X[(size_t)row * D + k];
        s += v * v;
    }
    __shared__ float sm[256];
    sm[threadIdx.x] = s;
    __syncthreads();
    for (int off = 128; off > 0; off >>= 1) {
        if (threadIdx.x < off) sm[threadIdx.x] += sm[threadIdx.x + off];
        __syncthreads();
    }
    if (threadIdx.x == 0) O[row] = sm[0];
}

__global__ __launch_bounds__(256, 2)
void pair_mfma_kernel(const float* __restrict__ A,
                      const float* __restrict__ B,
                      const float* __restrict__ a2,
                      const float* __restrict__ b2,
                      int D, float alpha, float beta, int sym,
                      double* __restrict__ part)
{
    const int bx = blockIdx.x;
    const int by = blockIdx.y;
    const int t  = threadIdx.x;
    if (sym && bx < by) {
        if (t == 0) part[(size_t)by * NBT + bx] = 0.0;
        return;
    }
    const int lane = t & 63;
    const int wave = t >> 6;
    const int wm = wave >> 1;
    const int wn = wave & 1;
    const int i0 = by * TILE;
    const int j0 = bx * TILE;

    __shared__ __align__(16) unsigned short As[TILE * 32];
    __shared__ __align__(16) unsigned short Bs[TILE * 32];

    f32x4 acc[4][4] = {};

    for (int k0 = 0; k0 < D; k0 += 32) {
        __syncthreads();
#pragma unroll
        for (int s = 0; s < 2; ++s) {
            const int g   = s * 256 + t;
            const int row = g >> 2;
            const int kb  = k0 + (g & 3) * 8;

            float va[8], vb[8];
            const float* srcA = &A[(size_t)(i0 + row) * D + kb];
            const float* srcB = &B[(size_t)(j0 + row) * D + kb];
            if (kb + 8 <= D) {
                float4 a0 = *reinterpret_cast<const float4*>(srcA);
                float4 a1 = *reinterpret_cast<const float4*>(srcA + 4);
                va[0]=a0.x; va[1]=a0.y; va[2]=a0.z; va[3]=a0.w;
                va[4]=a1.x; va[5]=a1.y; va[6]=a1.z; va[7]=a1.w;
                float4 b0 = *reinterpret_cast<const float4*>(srcB);
                float4 b1 = *reinterpret_cast<const float4*>(srcB + 4);
                vb[0]=b0.x; vb[1]=b0.y; vb[2]=b0.z; vb[3]=b0.w;
                vb[4]=b1.x; vb[5]=b1.y; vb[6]=b1.z; vb[7]=b1.w;
            } else {
#pragma unroll
                for (int c = 0; c < 8; ++c) {
                    va[c] = (kb + c < D) ? srcA[c] : 0.f;
                    vb[c] = (kb + c < D) ? srcB[c] : 0.f;
                }
            }
            bf16x8 pa, pb;
#pragma unroll
            for (int c = 0; c < 8; ++c) {
                __hip_bfloat16 ha = __float2bfloat16(va[c]);
                __hip_bfloat16 hb = __float2bfloat16(vb[c]);
                pa[c] = *reinterpret_cast<short*>(&ha);
                pb[c] = *reinterpret_cast<short*>(&hb);
            }
            *reinterpret_cast<bf16x8*>(&As[g * 8]) = pa;
            *reinterpret_cast<bf16x8*>(&Bs[g * 8]) = pb;
        }
        __syncthreads();

        const int lr = lane & 15;
        const int kg = lane >> 4;
        bf16x8 af[4], bfr[4];
#pragma unroll
        for (int m = 0; m < 4; ++m)
            af[m] = *reinterpret_cast<const bf16x8*>(
                &As[(wm * 64 + m * 16 + lr) * 32 + kg * 8]);
#pragma unroll
        for (int n = 0; n < 4; ++n)
            bfr[n] = *reinterpret_cast<const bf16x8*>(
                &Bs[(wn * 64 + n * 16 + lr) * 32 + kg * 8]);
#pragma unroll
        for (int m = 0; m < 4; ++m)
#pragma unroll
            for (int n = 0; n < 4; ++n)
                acc[m][n] = __builtin_amdgcn_mfma_f32_16x16x32_bf16(
                    af[m], bfr[n], acc[m][n], 0, 0, 0);
    }

    float lsum = 0.f;
    const int cr = lane >> 4;
    const int cc = lane & 15;
#pragma unroll
    for (int m = 0; m < 4; ++m) {
#pragma unroll
        for (int n = 0; n < 4; ++n) {
#pragma unroll
            for (int q = 0; q < 4; ++q) {
                const int gi = i0 + wm * 64 + m * 16 + cr * 4 + q;
                const int gj = j0 + wn * 64 + n * 16 + cc;
                float d = a2[gi] + b2[gj] - 2.f * acc[m][n][q];
                d = fmaxf(d, 0.f);
                float x = alpha + beta * d;
                float r = __frsqrt_rn(x);
                r = r * (1.5f - 0.5f * x * r * r);
                lsum += r;
            }
        }
    }
    if (sym && bx > by) lsum *= 2.f;

    __shared__ float red[256];
    red[t] = lsum;
    __syncthreads();
    for (int off = 128; off > 0; off >>= 1) {
        if (t < off) red[t] += red[t + off];
        __syncthreads();
    }
    if (t == 0) part[(size_t)by * NBT + bx] = (double)red[0];
}

// ---------------------------------------------------------------------------
// Finalize (fast path): 3 region sums over NTRI + zz over NPARTS + z norms.
// ---------------------------------------------------------------------------
__global__ void finalize_tri(const double* __restrict__ parts3,
                             const double* __restrict__ partsZ,
                             const float* __restrict__ z2,
                             float* __restrict__ out)
{
    const int tid = threadIdx.x;
    double s0 = 0, s1 = 0, s2 = 0, s3 = 0, s4 = 0;
    for (int i = tid; i < NTRI; i += 256) {
        s0 += parts3[i];
        s1 += parts3[NTRI + i];
        s2 += parts3[2 * NTRI + i];
    }
    for (int i = tid; i < NPARTS; i += 256) s3 += partsZ[i];
    for (int i = tid; i < NROWS; i += 256) s4 += (double)z2[i];

    __shared__ double sm[256];
    double tot[5];
    double loc[5] = { s0, s1, s2, s3, s4 };
    for (int j = 0; j < 5; ++j) {
        sm[tid] = loc[j];
        __syncthreads();
        for (int off = 128; off > 0; off >>= 1) {
            if (tid < off) sm[tid] += sm[tid + off];
            __syncthreads();
        }
        tot[j] = sm[0];
        __syncthreads();
    }

    if (tid == 0) {
        const double Nn = (double)NROWS;
        const double n2 = Nn * Nn;
        const double y  = pow(4.0 / (3.0 * Nn), 0.4);

        double A = tot[0] / n2;
        double B = tot[1] / n2;
        double C = tot[2] / n2;
        double T = 1.0 / (2.0 * sqrt(M_PI * y));
        double loss_rec = log(T * (A + B - 2.0 * C));

        double An = tot[3] / n2;
        double B1 = tot[4];
        double Bn = 2.0 / sqrt(y + 0.5 + B1 / 125.0);
        double loss_norm = log(1.0 / sqrt(1.0 + y) + An - Bn);

        out[0] = (float)(loss_rec + loss_norm);
    }
}

// Finalize (slow path): round-3 layout (4 x NPARTS).
__global__ void finalize_kernel(const double* __restrict__ parts,
                                const float* __restrict__ z2,
                                float* __restrict__ out)
{
    const int tid = threadIdx.x;
    double s0 = 0, s1 = 0, s2 = 0, s3 = 0, s4 = 0;
    for (int i = tid; i < NPARTS; i += 256) {
        s0 += parts[i];
        s1 += parts[NPARTS + i];
        s2 += parts[2 * NPARTS + i];
        s3 += parts[3 * NPARTS + i];
    }
    for (int i = tid; i < NROWS; i += 256) s4 += (double)z2[i];

    __shared__ double sm[256];
    double tot[5];
    double loc[5] = { s0, s1, s2, s3, s4 };
    for (int j = 0; j < 5; ++j) {
        sm[tid] = loc[j];
        __syncthreads();
        for (int off = 128; off > 0; off >>= 1) {
            if (tid < off) sm[tid] += sm[tid + off];
            __syncthreads();
        }
        tot[j] = sm[0];
        __syncthreads();
    }

    if (tid == 0) {
        const double Nn = (double)NROWS;
        const double n2 = Nn * Nn;
        const double y  = pow(4.0 / (3.0 * Nn), 0.4);

        double A = tot[0] / n2;
        double B = tot[1] / n2;
        double C = tot[2] / n2;
        double T = 1.0 / (2.0 * sqrt(M_PI * y));
        double loss_rec = log(T * (A + B - 2.0 * C));

        double An = tot[3] / n2;
        double B1 = tot[4];
        double Bn = 2.0 / sqrt(y + 0.5 + B1 / 125.0);
        double loss_norm = log(1.0 / sqrt(1.0 + y) + An - Bn);

        out[0] = (float)(loss_rec + loss_norm);
    }
}

// ---------------------------------------------------------------------------
extern "C" void kernel_launch(void* const* d_in, const int* in_sizes, int n_in,
                              void* d_out, int out_size, void* d_ws, size_t ws_size,
                              hipStream_t stream)
{
    const float* data = (const float*)d_in[0];
    const float* rec  = (const float*)d_in[1];
    const float* z    = (const float*)d_in[2];
    float* out = (float*)d_out;

    // ws layout: [parts (3*NTRI + NPARTS doubles, >= slow's 4*NPARTS)]
    //            [a2d a2r a2z][dat_bf rec_bf (concat) z_bf]
    const size_t PARTS_DBL = (size_t)3 * NTRI + NPARTS;   // 28864 doubles
    char* ws = (char*)d_ws;
    double* parts3 = (double*)ws;
    double* partsZ = parts3 + (size_t)3 * NTRI;
    float*  a2d    = (float*)(parts3 + PARTS_DBL);
    float*  a2r    = a2d + NROWS;     // adjacent: [a2d;a2r] = concat norms
    float*  a2z    = a2r + NROWS;
    unsigned short* dat_bf = (unsigned short*)(a2z + NROWS);
    unsigned short* rec_bf = dat_bf + (size_t)NROWS * LDK_D;  // adjacent: concat
    unsigned short* z_bf   = rec_bf + (size_t)NROWS * LDK_D;

    const size_t base_need = PARTS_DBL * sizeof(double) + 3 * (size_t)NROWS * sizeof(float);
    const size_t full_need = base_need +
        (2 * (size_t)NROWS * LDK_D + (size_t)NROWS * DLAT) * sizeof(unsigned short);
    const bool fast = (ws_size >= full_need);

    const double y = pow(4.0 / (3.0 * (double)NROWS), 0.4);
    const float beta_s = (float)(1.0 / (1565.0 * y));   // 2*DDAT-3 = 1565

    if (fast) {
        hipMemsetAsync(parts3, 0, PARTS_DBL * sizeof(double), stream);
        convert_kernel<<<dim3(NROWS, 3), 256, 0, stream>>>(
            data, rec, z, dat_bf, rec_bf, z_bf, a2d, a2r, a2z);
        // dd + rr + dr in one triangular launch over concat [data; rec]
        pair_mfma_tri<<<NTRI, 256, 0, stream>>>(
            dat_bf, a2d, 1.0f, beta_s, parts3);
        // normality: z-z (symmetric), phi = rsqrt(y + dist/125)
        pair_mfma_fast<<<dim3(NBT, NBT), 256, 0, stream>>>(
            z_bf, z_bf, a2z, a2z, DLAT, (float)y, 1.0f / 125.0f, 1, partsZ);
        finalize_tri<<<1, 256, 0, stream>>>(parts3, partsZ, a2z, out);
    } else {
        double* parts = parts3;   // slow layout: 4 x NPARTS
        hipMemsetAsync(parts, 0, 4 * (size_t)NPARTS * sizeof(double), stream);
        rownorm_kernel<<<dim3(NROWS, 3), 256, 0, stream>>>(
            data, rec, z, a2d, a2r, a2z);
        dim3 grid(NBT, NBT);
        pair_mfma_kernel<<<grid, 256, 0, stream>>>(
            data, data, a2d, a2d, DDAT, 1.0f, beta_s, 1, parts);
        pair_mfma_kernel<<<grid, 256, 0, stream>>>(
            rec, rec, a2r, a2r, DDAT, 1.0f, beta_s, 1, parts + NPARTS);
        pair_mfma_kernel<<<grid, 256, 0, stream>>>(
            data, rec, a2d, a2r, DDAT, 1.0f, beta_s, 0, parts + 2 * NPARTS);
        pair_mfma_kernel<<<grid, 256, 0, stream>>>(
            z, z, a2z, a2z, DLAT, (float)y, 1.0f / 125.0f, 1, parts + 3 * NPARTS);
        finalize_kernel<<<1, 256, 0, stream>>>(parts, a2z, out);
    }
}

// Round 7
// 317.972 us; speedup vs baseline: 1.1511x; 1.1511x over previous
//
#include <hip/hip_runtime.h>
#include <hip/hip_bf16.h>
#include <math.h>

// Problem constants
#define NROWS 8192
#define DDAT  784
#define LDK_D 800            // padded K (multiple of 32)
#define DLAT  64
#define TILE  128            // output tile per block
#define NBT   64             // zz grid dim: 8192/128
#define NPARTS (NBT * NBT)   // 4096 zz partial slots
#define NBTC  128            // concat rows 16384 / 128
// Supertile decomposition of the 128x128 block triangle:
#define SG    8              // supertile = 8x8 blocks
#define NSB   (NBTC / SG)    // 16 supertiles per dim
#define NST   (NSB * (NSB + 1) / 2)   // 136 supertiles (incl diagonal)
#define NSLOT (NST * SG * SG)         // 8704 launch slots
#define CHUNK (NSLOT / 8)             // 1088 per XCD (exact)

typedef __attribute__((ext_vector_type(8))) short bf16x8;
typedef __attribute__((ext_vector_type(4))) float f32x4;

__device__ __forceinline__ void gload_lds16(const void* g, void* l) {
    __builtin_amdgcn_global_load_lds(
        (const __attribute__((address_space(1))) unsigned int*)g,
        (__attribute__((address_space(3))) unsigned int*)l,
        16 /*bytes*/, 0, 0);
}

// ---------------------------------------------------------------------------
// fp32 -> bf16 (zero-padded to LDK) + exact fp32 row norms, fused.
// grid = (8192, 3), block = 256.
// ---------------------------------------------------------------------------
__global__ void convert_kernel(const float* __restrict__ dat,
                               const float* __restrict__ rec,
                               const float* __restrict__ z,
                               unsigned short* __restrict__ dat_bf,
                               unsigned short* __restrict__ rec_bf,
                               unsigned short* __restrict__ z_bf,
                               float* __restrict__ a2d,
                               float* __restrict__ a2r,
                               float* __restrict__ a2z)
{
    const float* X; unsigned short* O; float* N2; int D, LDK;
    if (blockIdx.y == 0)      { X = dat; O = dat_bf; N2 = a2d; D = DDAT; LDK = LDK_D; }
    else if (blockIdx.y == 1) { X = rec; O = rec_bf; N2 = a2r; D = DDAT; LDK = LDK_D; }
    else                      { X = z;   O = z_bf;   N2 = a2z; D = DLAT; LDK = DLAT; }

    const int row = blockIdx.x;
    float s = 0.f;
    for (int k = threadIdx.x; k < LDK; k += 256) {
        float v = (k < D) ? X[(size_t)row * D + k] : 0.f;
        __hip_bfloat16 h = __float2bfloat16(v);
        O[(size_t)row * LDK + k] = *reinterpret_cast<unsigned short*>(&h);
        s += v * v;
    }
    __shared__ float sm[256];
    sm[threadIdx.x] = s;
    __syncthreads();
    for (int off = 128; off > 0; off >>= 1) {
        if (threadIdx.x < off) sm[threadIdx.x] += sm[threadIdx.x + off];
        __syncthreads();
    }
    if (threadIdx.x == 0) N2[row] = sm[0];
}

// ---------------------------------------------------------------------------
// [fast path] Merged triangular MFMA pairwise-phi kernel over the
// concatenated [data; rec] bf16 matrix (16384 x LDK_D).
//
// L2-locality remap: the 128x128 block triangle is decomposed into 8x8-block
// SUPERTILES (3.2 MB panel working set ~ one XCD L2). 136 supertiles x 64
// slots = 8704 launch slots; diagonal supertiles idle their by>bx slots (5%).
// XCD-chunked bijection swz = (lin&7)*CHUNK + lin>>3 gives each XCD a
// contiguous run of ~17 supertiles along a supertile row, so A-panels persist
// in its L2 while B-panels stream through a 1.6 MB window.
//
// Pipeline: 2-phase double-buffer (stage k+1 before computing k;
// vmcnt(0)+barrier at iter end — race-free by parity).
// Bank-conflict fix (rule #21): LDS linear; global source chunk permuted
// halfS = half ^ ((row>>1)&3); fragment read slot = kg ^ ((lr>>1)&3).
// Verified round 6: SQ_LDS_BANK_CONFLICT == 0.
// ---------------------------------------------------------------------------
__global__ __launch_bounds__(256, 2)
void pair_mfma_tri(const unsigned short* __restrict__ cat,  // 16384 x LDK_D
                   const float* __restrict__ n2,            // 16384
                   float alpha, float beta,
                   double* __restrict__ part)               // 3 * NSLOT
{
    const int lin = blockIdx.x;
    const int swz = (lin & 7) * CHUNK + (lin >> 3);   // XCD-chunked bijection
    const int st  = swz >> 6;                         // supertile id (0..135)
    const int blk = swz & 63;                         // slot within supertile

    // Triangular row-major decode: supertile (sby, sbx), sby <= sbx.
    int sby = 0, rem = st;
    while (rem >= NSB - sby) { rem -= NSB - sby; ++sby; }
    const int sbx = sby + rem;

    const int by = sby * SG + (blk >> 3);
    const int bx = sbx * SG + (blk & 7);
    if (by > bx) return;    // idle slot of a diagonal supertile (parts pre-zeroed)

    int region; float w;
    if (bx < NBTC / 2)       { region = 0; w = (bx == by) ? 1.f : 2.f; }   // dd
    else if (by >= NBTC / 2) { region = 1; w = (bx == by) ? 1.f : 2.f; }   // rr
    else                     { region = 2; w = 1.f; }                      // dr

    const int t    = threadIdx.x;
    const int lane = t & 63;
    const int wave = t >> 6;
    const int wm = wave >> 1;    // wave row (0..1)
    const int wn = wave & 1;     // wave col (0..1)
    const size_t i0 = (size_t)by * TILE;
    const size_t j0 = (size_t)bx * TILE;

    __shared__ __align__(16) unsigned short As[2][TILE * 32];
    __shared__ __align__(16) unsigned short Bs[2][TILE * 32];

    f32x4 acc[4][4] = {};

    auto stage = [&](int P, int K0) {
#pragma unroll
        for (int s = 0; s < 2; ++s) {
            const int g     = s * 256 + t;
            const int row   = g >> 2;
            const int halfS = (g & 3) ^ ((row >> 1) & 3);
            const int ldsbase = (s * 256 + wave * 64) * 8;   // in shorts
            gload_lds16(&cat[(i0 + row) * LDK_D + K0 + halfS * 8], &As[P][ldsbase]);
            gload_lds16(&cat[(j0 + row) * LDK_D + K0 + halfS * 8], &Bs[P][ldsbase]);
        }
    };

    // Prologue: stage tile 0, drain, barrier.
    stage(0, 0);
    asm volatile("s_waitcnt vmcnt(0)" ::: "memory");
    __builtin_amdgcn_sched_barrier(0);
    __syncthreads();

    int p = 0;
    for (int k0 = 0; k0 < LDK_D; k0 += 32) {
        if (k0 + 32 < LDK_D) stage(p ^ 1, k0 + 32);   // prefetch next tile

        const int lr   = lane & 15;
        const int kg   = lane >> 4;
        const int slot = kg ^ ((lr >> 1) & 3);        // read-side swizzle
        bf16x8 af[4], bfr[4];
#pragma unroll
        for (int m = 0; m < 4; ++m)
            af[m] = *reinterpret_cast<const bf16x8*>(
                &As[p][(wm * 64 + m * 16 + lr) * 32 + slot * 8]);
#pragma unroll
        for (int n = 0; n < 4; ++n)
            bfr[n] = *reinterpret_cast<const bf16x8*>(
                &Bs[p][(wn * 64 + n * 16 + lr) * 32 + slot * 8]);
#pragma unroll
        for (int m = 0; m < 4; ++m)
#pragma unroll
            for (int n = 0; n < 4; ++n)
                acc[m][n] = __builtin_amdgcn_mfma_f32_16x16x32_bf16(
                    af[m], bfr[n], acc[m][n], 0, 0, 0);

        asm volatile("s_waitcnt vmcnt(0)" ::: "memory");
        __builtin_amdgcn_sched_barrier(0);
        __syncthreads();
        p ^= 1;
    }

    // Epilogue: C/D layout col = lane&15, row = (lane>>4)*4 + q  [m89/m91]
    float lsum = 0.f;
    const int cr = lane >> 4;
    const int cc = lane & 15;
#pragma unroll
    for (int m = 0; m < 4; ++m) {
#pragma unroll
        for (int n = 0; n < 4; ++n) {
#pragma unroll
            for (int q = 0; q < 4; ++q) {
                const int gi = (int)i0 + wm * 64 + m * 16 + cr * 4 + q;
                const int gj = (int)j0 + wn * 64 + n * 16 + cc;
                float d = n2[gi] + n2[gj] - 2.f * acc[m][n][q];
                d = fmaxf(d, 0.f);
                float x = alpha + beta * d;
                float r = __frsqrt_rn(x);
                r = r * (1.5f - 0.5f * x * r * r);   // one Newton step
                lsum += r;
            }
        }
    }
    lsum *= w;

    __shared__ float red[256];
    red[t] = lsum;
    __syncthreads();
    for (int off = 128; off > 0; off >>= 1) {
        if (t < off) red[t] += red[t + off];
        __syncthreads();
    }
    if (t == 0) part[(size_t)region * NSLOT + swz] = (double)red[0];
}

// ---------------------------------------------------------------------------
// [fast path, zz] round-5 verified kernel, verbatim (small: K=64).
// ---------------------------------------------------------------------------
__global__ __launch_bounds__(256, 2)
void pair_mfma_fast(const unsigned short* __restrict__ A,
                    const unsigned short* __restrict__ B,
                    const float* __restrict__ a2,
                    const float* __restrict__ b2,
                    int LDK, float alpha, float beta, int sym,
                    double* __restrict__ part)
{
    const int bx = blockIdx.x;
    const int by = blockIdx.y;
    const int t  = threadIdx.x;
    if (sym && bx < by) {
        if (t == 0) part[(size_t)by * NBT + bx] = 0.0;
        return;
    }
    const int lane = t & 63;
    const int wave = t >> 6;
    const int wm = wave >> 1;
    const int wn = wave & 1;
    const int i0 = by * TILE;
    const int j0 = bx * TILE;

    __shared__ __align__(16) unsigned short As[2][TILE * 32];
    __shared__ __align__(16) unsigned short Bs[2][TILE * 32];

    f32x4 acc[4][4] = {};

    int p = 0;
    for (int k0 = 0; k0 < LDK; k0 += 32, p ^= 1) {
#pragma unroll
        for (int s = 0; s < 2; ++s) {
            const int g    = s * 256 + t;
            const int row  = g >> 2;
            const int half = g & 3;
            const int ldsbase = (s * 256 + wave * 64) * 8;
            gload_lds16(&A[(size_t)(i0 + row) * LDK + k0 + half * 8], &As[p][ldsbase]);
            gload_lds16(&B[(size_t)(j0 + row) * LDK + k0 + half * 8], &Bs[p][ldsbase]);
        }
        asm volatile("s_waitcnt vmcnt(0)" ::: "memory");
        __builtin_amdgcn_sched_barrier(0);
        __syncthreads();

        const int lr = lane & 15;
        const int kg = lane >> 4;
        bf16x8 af[4], bfr[4];
#pragma unroll
        for (int m = 0; m < 4; ++m)
            af[m] = *reinterpret_cast<const bf16x8*>(
                &As[p][(wm * 64 + m * 16 + lr) * 32 + kg * 8]);
#pragma unroll
        for (int n = 0; n < 4; ++n)
            bfr[n] = *reinterpret_cast<const bf16x8*>(
                &Bs[p][(wn * 64 + n * 16 + lr) * 32 + kg * 8]);
#pragma unroll
        for (int m = 0; m < 4; ++m)
#pragma unroll
            for (int n = 0; n < 4; ++n)
                acc[m][n] = __builtin_amdgcn_mfma_f32_16x16x32_bf16(
                    af[m], bfr[n], acc[m][n], 0, 0, 0);
    }

    float lsum = 0.f;
    const int cr = lane >> 4;
    const int cc = lane & 15;
#pragma unroll
    for (int m = 0; m < 4; ++m) {
#pragma unroll
        for (int n = 0; n < 4; ++n) {
#pragma unroll
            for (int q = 0; q < 4; ++q) {
                const int gi = i0 + wm * 64 + m * 16 + cr * 4 + q;
                const int gj = j0 + wn * 64 + n * 16 + cc;
                float d = a2[gi] + b2[gj] - 2.f * acc[m][n][q];
                d = fmaxf(d, 0.f);
                float x = alpha + beta * d;
                float r = __frsqrt_rn(x);
                r = r * (1.5f - 0.5f * x * r * r);
                lsum += r;
            }
        }
    }
    if (sym && bx > by) lsum *= 2.f;

    __shared__ float red[256];
    red[t] = lsum;
    __syncthreads();
    for (int off = 128; off > 0; off >>= 1) {
        if (t < off) red[t] += red[t + off];
        __syncthreads();
    }
    if (t == 0) part[(size_t)by * NBT + bx] = (double)red[0];
}

// ---------------------------------------------------------------------------
// [slow path fallback] round-3 verified kernels, verbatim.
// ---------------------------------------------------------------------------
__global__ void rownorm_kernel(const float* __restrict__ dat,
                               const float* __restrict__ rec,
                               const float* __restrict__ z,
                               float* __restrict__ o_dat,
                               float* __restrict__ o_rec,
                               float* __restrict__ o_z)
{
    const float* X; float* O; int D;
    if (blockIdx.y == 0)      { X = dat; O = o_dat; D = DDAT; }
    else if (blockIdx.y == 1) { X = rec; O = o_rec; D = DDAT; }
    else                      { X = z;   O = o_z;   D = DLAT; }

    int row = blockIdx.x;
    float s = 0.f;
    for (int k = threadIdx.x; k < D; k += 256) {
        float v = X[(size_t)row * D + k];
        s += v * v;
    }
    __shared__ float sm[256];
    sm[threadIdx.x] = s;
    __syncthreads();
    for (int off = 128; off > 0; off >>= 1) {
        if (threadIdx.x < off) sm[threadIdx.x] += sm[threadIdx.x + off];
        __syncthreads();
    }
    if (threadIdx.x == 0) O[row] = sm[0];
}

__global__ __launch_bounds__(256, 2)
void pair_mfma_kernel(const float* __restrict__ A,
                      const float* __restrict__ B,
                      const float* __restrict__ a2,
                      const float* __restrict__ b2,
                      int D, float alpha, float beta, int sym,
                      double* __restrict__ part)
{
    const int bx = blockIdx.x;
    const int by = blockIdx.y;
    const int t  = threadIdx.x;
    if (sym && bx < by) {
        if (t == 0) part[(size_t)by * NBT + bx] = 0.0;
        return;
    }
    const int lane = t & 63;
    const int wave = t >> 6;
    const int wm = wave >> 1;
    const int wn = wave & 1;
    const int i0 = by * TILE;
    const int j0 = bx * TILE;

    __shared__ __align__(16) unsigned short As[TILE * 32];
    __shared__ __align__(16) unsigned short Bs[TILE * 32];

    f32x4 acc[4][4] = {};

    for (int k0 = 0; k0 < D; k0 += 32) {
        __syncthreads();
#pragma unroll
        for (int s = 0; s < 2; ++s) {
            const int g   = s * 256 + t;
            const int row = g >> 2;
            const int kb  = k0 + (g & 3) * 8;

            float va[8], vb[8];
            const float* srcA = &A[(size_t)(i0 + row) * D + kb];
            const float* srcB = &B[(size_t)(j0 + row) * D + kb];
            if (kb + 8 <= D) {
                float4 a0 = *reinterpret_cast<const float4*>(srcA);
                float4 a1 = *reinterpret_cast<const float4*>(srcA + 4);
                va[0]=a0.x; va[1]=a0.y; va[2]=a0.z; va[3]=a0.w;
                va[4]=a1.x; va[5]=a1.y; va[6]=a1.z; va[7]=a1.w;
                float4 b0 = *reinterpret_cast<const float4*>(srcB);
                float4 b1 = *reinterpret_cast<const float4*>(srcB + 4);
                vb[0]=b0.x; vb[1]=b0.y; vb[2]=b0.z; vb[3]=b0.w;
                vb[4]=b1.x; vb[5]=b1.y; vb[6]=b1.z; vb[7]=b1.w;
            } else {
#pragma unroll
                for (int c = 0; c < 8; ++c) {
                    va[c] = (kb + c < D) ? srcA[c] : 0.f;
                    vb[c] = (kb + c < D) ? srcB[c] : 0.f;
                }
            }
            bf16x8 pa, pb;
#pragma unroll
            for (int c = 0; c < 8; ++c) {
                __hip_bfloat16 ha = __float2bfloat16(va[c]);
                __hip_bfloat16 hb = __float2bfloat16(vb[c]);
                pa[c] = *reinterpret_cast<short*>(&ha);
                pb[c] = *reinterpret_cast<short*>(&hb);
            }
            *reinterpret_cast<bf16x8*>(&As[g * 8]) = pa;
            *reinterpret_cast<bf16x8*>(&Bs[g * 8]) = pb;
        }
        __syncthreads();

        const int lr = lane & 15;
        const int kg = lane >> 4;
        bf16x8 af[4], bfr[4];
#pragma unroll
        for (int m = 0; m < 4; ++m)
            af[m] = *reinterpret_cast<const bf16x8*>(
                &As[(wm * 64 + m * 16 + lr) * 32 + kg * 8]);
#pragma unroll
        for (int n = 0; n < 4; ++n)
            bfr[n] = *reinterpret_cast<const bf16x8*>(
                &Bs[(wn * 64 + n * 16 + lr) * 32 + kg * 8]);
#pragma unroll
        for (int m = 0; m < 4; ++m)
#pragma unroll
            for (int n = 0; n < 4; ++n)
                acc[m][n] = __builtin_amdgcn_mfma_f32_16x16x32_bf16(
                    af[m], bfr[n], acc[m][n], 0, 0, 0);
    }

    float lsum = 0.f;
    const int cr = lane >> 4;
    const int cc = lane & 15;
#pragma unroll
    for (int m = 0; m < 4; ++m) {
#pragma unroll
        for (int n = 0; n < 4; ++n) {
#pragma unroll
            for (int q = 0; q < 4; ++q) {
                const int gi = i0 + wm * 64 + m * 16 + cr * 4 + q;
                const int gj = j0 + wn * 64 + n * 16 + cc;
                float d = a2[gi] + b2[gj] - 2.f * acc[m][n][q];
                d = fmaxf(d, 0.f);
                float x = alpha + beta * d;
                float r = __frsqrt_rn(x);
                r = r * (1.5f - 0.5f * x * r * r);
                lsum += r;
            }
        }
    }
    if (sym && bx > by) lsum *= 2.f;

    __shared__ float red[256];
    red[t] = lsum;
    __syncthreads();
    for (int off = 128; off > 0; off >>= 1) {
        if (t < off) red[t] += red[t + off];
        __syncthreads();
    }
    if (t == 0) part[(size_t)by * NBT + bx] = (double)red[0];
}

// ---------------------------------------------------------------------------
// Finalize (fast path): 3 region sums over NSLOT + zz over NPARTS + z norms.
// ---------------------------------------------------------------------------
__global__ void finalize_tri(const double* __restrict__ parts3,
                             const double* __restrict__ partsZ,
                             const float* __restrict__ z2,
                             float* __restrict__ out)
{
    const int tid = threadIdx.x;
    double s0 = 0, s1 = 0, s2 = 0, s3 = 0, s4 = 0;
    for (int i = tid; i < NSLOT; i += 256) {
        s0 += parts3[i];
        s1 += parts3[NSLOT + i];
        s2 += parts3[2 * NSLOT + i];
    }
    for (int i = tid; i < NPARTS; i += 256) s3 += partsZ[i];
    for (int i = tid; i < NROWS; i += 256) s4 += (double)z2[i];

    __shared__ double sm[256];
    double tot[5];
    double loc[5] = { s0, s1, s2, s3, s4 };
    for (int j = 0; j < 5; ++j) {
        sm[tid] = loc[j];
        __syncthreads();
        for (int off = 128; off > 0; off >>= 1) {
            if (tid < off) sm[tid] += sm[tid + off];
            __syncthreads();
        }
        tot[j] = sm[0];
        __syncthreads();
    }

    if (tid == 0) {
        const double Nn = (double)NROWS;
        const double n2 = Nn * Nn;
        const double y  = pow(4.0 / (3.0 * Nn), 0.4);

        double A = tot[0] / n2;
        double B = tot[1] / n2;
        double C = tot[2] / n2;
        double T = 1.0 / (2.0 * sqrt(M_PI * y));
        double loss_rec = log(T * (A + B - 2.0 * C));

        double An = tot[3] / n2;
        double B1 = tot[4];
        double Bn = 2.0 / sqrt(y + 0.5 + B1 / 125.0);
        double loss_norm = log(1.0 / sqrt(1.0 + y) + An - Bn);

        out[0] = (float)(loss_rec + loss_norm);
    }
}

// Finalize (slow path): round-3 layout (4 x NPARTS).
__global__ void finalize_kernel(const double* __restrict__ parts,
                                const float* __restrict__ z2,
                                float* __restrict__ out)
{
    const int tid = threadIdx.x;
    double s0 = 0, s1 = 0, s2 = 0, s3 = 0, s4 = 0;
    for (int i = tid; i < NPARTS; i += 256) {
        s0 += parts[i];
        s1 += parts[NPARTS + i];
        s2 += parts[2 * NPARTS + i];
        s3 += parts[3 * NPARTS + i];
    }
    for (int i = tid; i < NROWS; i += 256) s4 += (double)z2[i];

    __shared__ double sm[256];
    double tot[5];
    double loc[5] = { s0, s1, s2, s3, s4 };
    for (int j = 0; j < 5; ++j) {
        sm[tid] = loc[j];
        __syncthreads();
        for (int off = 128; off > 0; off >>= 1) {
            if (tid < off) sm[tid] += sm[tid + off];
            __syncthreads();
        }
        tot[j] = sm[0];
        __syncthreads();
    }

    if (tid == 0) {
        const double Nn = (double)NROWS;
        const double n2 = Nn * Nn;
        const double y  = pow(4.0 / (3.0 * Nn), 0.4);

        double A = tot[0] / n2;
        double B = tot[1] / n2;
        double C = tot[2] / n2;
        double T = 1.0 / (2.0 * sqrt(M_PI * y));
        double loss_rec = log(T * (A + B - 2.0 * C));

        double An = tot[3] / n2;
        double B1 = tot[4];
        double Bn = 2.0 / sqrt(y + 0.5 + B1 / 125.0);
        double loss_norm = log(1.0 / sqrt(1.0 + y) + An - Bn);

        out[0] = (float)(loss_rec + loss_norm);
    }
}

// ---------------------------------------------------------------------------
extern "C" void kernel_launch(void* const* d_in, const int* in_sizes, int n_in,
                              void* d_out, int out_size, void* d_ws, size_t ws_size,
                              hipStream_t stream)
{
    const float* data = (const float*)d_in[0];
    const float* rec  = (const float*)d_in[1];
    const float* z    = (const float*)d_in[2];
    float* out = (float*)d_out;

    // ws layout: [parts (3*NSLOT + NPARTS doubles, >= slow's 4*NPARTS)]
    //            [a2d a2r a2z][dat_bf rec_bf (concat) z_bf]
    const size_t PARTS_DBL = (size_t)3 * NSLOT + NPARTS;   // 30208 doubles
    char* ws = (char*)d_ws;
    double* parts3 = (double*)ws;
    double* partsZ = parts3 + (size_t)3 * NSLOT;
    float*  a2d    = (float*)(parts3 + PARTS_DBL);
    float*  a2r    = a2d + NROWS;     // adjacent: [a2d;a2r] = concat norms
    float*  a2z    = a2r + NROWS;
    unsigned short* dat_bf = (unsigned short*)(a2z + NROWS);
    unsigned short* rec_bf = dat_bf + (size_t)NROWS * LDK_D;  // adjacent: concat
    unsigned short* z_bf   = rec_bf + (size_t)NROWS * LDK_D;

    const size_t base_need = PARTS_DBL * sizeof(double) + 3 * (size_t)NROWS * sizeof(float);
    const size_t full_need = base_need +
        (2 * (size_t)NROWS * LDK_D + (size_t)NROWS * DLAT) * sizeof(unsigned short);
    const bool fast = (ws_size >= full_need);

    const double y = pow(4.0 / (3.0 * (double)NROWS), 0.4);
    const float beta_s = (float)(1.0 / (1565.0 * y));   // 2*DDAT-3 = 1565

    if (fast) {
        hipMemsetAsync(parts3, 0, PARTS_DBL * sizeof(double), stream);
        convert_kernel<<<dim3(NROWS, 3), 256, 0, stream>>>(
            data, rec, z, dat_bf, rec_bf, z_bf, a2d, a2r, a2z);
        // dd + rr + dr in one supertiled triangular launch over concat
        pair_mfma_tri<<<NSLOT, 256, 0, stream>>>(
            dat_bf, a2d, 1.0f, beta_s, parts3);
        // normality: z-z (symmetric), phi = rsqrt(y + dist/125)
        pair_mfma_fast<<<dim3(NBT, NBT), 256, 0, stream>>>(
            z_bf, z_bf, a2z, a2z, DLAT, (float)y, 1.0f / 125.0f, 1, partsZ);
        finalize_tri<<<1, 256, 0, stream>>>(parts3, partsZ, a2z, out);
    } else {
        double* parts = parts3;   // slow layout: 4 x NPARTS
        hipMemsetAsync(parts, 0, 4 * (size_t)NPARTS * sizeof(double), stream);
        rownorm_kernel<<<dim3(NROWS, 3), 256, 0, stream>>>(
            data, rec, z, a2d, a2r, a2z);
        dim3 grid(NBT, NBT);
        pair_mfma_kernel<<<grid, 256, 0, stream>>>(
            data, data, a2d, a2d, DDAT, 1.0f, beta_s, 1, parts);
        pair_mfma_kernel<<<grid, 256, 0, stream>>>(
            rec, rec, a2r, a2r, DDAT, 1.0f, beta_s, 1, parts + NPARTS);
        pair_mfma_kernel<<<grid, 256, 0, stream>>>(
            data, rec, a2d, a2r, DDAT, 1.0f, beta_s, 0, parts + 2 * NPARTS);
        pair_mfma_kernel<<<grid, 256, 0, stream>>>(
            z, z, a2z, a2z, DLAT, (float)y, 1.0f / 125.0f, 1, parts + 3 * NPARTS);
        finalize_kernel<<<1, 256, 0, stream>>>(parts, a2z, out);
    }
}